// Round 4
// baseline (327.839 us; speedup 1.0000x reference)
//
#include <hip/hip_runtime.h>
#include <hip/hip_bf16.h>
#include <stdint.h>

// QSCrossAttention: B=8, Nq=1024, Nkv=4096, D=512, fp32 I/O, bf16 MFMA compute.
// R12: double-buffered 2-phase K-loops (T3 minimum recipe, m230/m248v2):
//      read frags from buf[cur] -> issue gload_lds of tile t+1 into buf[cur^1]
//      -> MFMA -> ONE __syncthreads. The barrier's vmcnt(0) drain now waits on
//      a prefetch that had the whole compute phase to land (R11 exposed the
//      full load latency between its two barriers). gemm_bt LDS 64KB (2 blk/CU),
//      pv_direct 48KB (3 blk/CU). Mask sniff = proven 3-mode device sniff.

typedef __bf16 bf16;
typedef bf16 bf16x8 __attribute__((ext_vector_type(8)));
typedef bf16 bf16x4 __attribute__((ext_vector_type(4)));
typedef float f32x4 __attribute__((ext_vector_type(4)));

#define NB 8
#define NQ 1024
#define NKV 4096
#define DD 512
#define RT_LD 136  // repack leading dim for 128-col tiles (272B rows)

// Async global->LDS, 16B per lane. g is per-lane global src; l must be the
// WAVE-UNIFORM LDS base (HW deposits at base + lane*16).
__device__ __forceinline__ void lds16(const bf16* g, bf16* l) {
  __builtin_amdgcn_global_load_lds(
      (const __attribute__((address_space(1))) unsigned int*)g,
      (__attribute__((address_space(3))) unsigned int*)l, 16, 0, 0);
}

// ---- scan_mask: 3-mode sniff + denom zero + per-batch prefix scan ---------
// mode 0: int32 0/1; mode 1: float 0.0/1.0; mode 2: bytes.
__global__ void scan_mask(const void* __restrict__ mask,
                          int* __restrict__ idx, int* __restrict__ cnt,
                          int* __restrict__ kpad, float* __restrict__ denom) {
  const int b = blockIdx.x, tid = threadIdx.x;
  // zero this batch's denominators
  for (int i = tid; i < NQ; i += 256) denom[b * NQ + i] = 0.f;

  // sniff the first 8192 words (32KB) -- whole byte-mask / prefix of word-mask
  __shared__ int s0, s1;
  if (tid == 0) { s0 = 0; s1 = 0; }
  __syncthreads();
  {
    const unsigned* mw = (const unsigned*)mask;
    int b0 = 0, b1 = 0;
    for (int i = tid; i < 8192; i += 256) {
      unsigned v = mw[i];
      if (v > 1u) b0 = 1;
      if (v != 0u && v != 0x3F800000u) b1 = 1;
    }
    if (b0) atomicOr(&s0, 1);
    if (b1) atomicOr(&s1, 1);
  }
  __syncthreads();
  const int mode = (s0 == 0) ? 0 : ((s1 == 0) ? 1 : 2);

  __shared__ int ps[256];
  unsigned bits = 0;
  int c = 0;
  const int base = tid * 16;
  for (int i = 0; i < 16; ++i) {
    const int col = base + i;
    bool k;
    if (mode == 0)      k = ((const int*)mask)[b * NKV + col] != 0;
    else if (mode == 1) k = ((const float*)mask)[b * NKV + col] != 0.f;
    else                k = ((const unsigned char*)mask)[b * NKV + col] != 0;
    bits |= (unsigned)k << i;
    c += k;
  }
  ps[tid] = c;
  __syncthreads();
  for (int s = 1; s < 256; s <<= 1) {
    int v = (tid >= s) ? ps[tid - s] : 0;
    __syncthreads();
    ps[tid] += v;
    __syncthreads();
  }
  int off = ps[tid] - c;
  for (int i = 0; i < 16; ++i)
    if ((bits >> i) & 1) idx[b * NKV + off++] = base + i;
  if (tid == 255) {
    cnt[b] = ps[255];
    kpad[b] = (ps[255] + 127) & ~127;
  }
}

// ---- prep: gather_qx (blk<2048) | cvt proto (<6144) | cvt weights ---------
__global__ void prep(const float* __restrict__ qx, const int* __restrict__ idx,
                     const int* __restrict__ cnt, const int* __restrict__ kpad,
                     bf16* __restrict__ qc,
                     const float* __restrict__ proto, bf16* __restrict__ proto_b,
                     const float* __restrict__ Wq, const float* __restrict__ Wk,
                     const float* __restrict__ Wv, const float* __restrict__ Wp,
                     bf16* __restrict__ Wq_b, bf16* __restrict__ Wkv_b,
                     bf16* __restrict__ Wp_b) {
  const int blk = blockIdx.x, tid = threadIdx.x;
  if (blk < 2048) {
    // gather: qc[b][r] = bf16(qx[b][idx[b][r]]) for r<cnt, zeros r in [cnt,kpad)
    const int b = blk >> 8, bx = blk & 255;
    const int wave = tid >> 6, lane = tid & 63;
    const int r0 = bx * 16 + wave * 4;
    const int n = cnt[b];
    const int kp = kpad[b];
#pragma unroll
    for (int j = 0; j < 4; ++j) {
      const int row = r0 + j;
      if (row >= kp) return;
      bf16x4* d = (bf16x4*)(qc + ((long)b * NKV + row) * DD) + lane;
      if (row < n) {
        const int src = idx[b * NKV + row];
        const float4* s = (const float4*)(qx + ((long)b * NKV + src) * DD) + lane;
        float4 v0 = s[0], v1 = s[64];
        bf16x4 o0, o1;
        o0.x = (bf16)v0.x; o0.y = (bf16)v0.y; o0.z = (bf16)v0.z; o0.w = (bf16)v0.w;
        o1.x = (bf16)v1.x; o1.y = (bf16)v1.y; o1.z = (bf16)v1.z; o1.w = (bf16)v1.w;
        d[0] = o0;
        d[64] = o1;
      } else {
        bf16x4 z;
        z.x = (bf16)0.f; z.y = (bf16)0.f; z.z = (bf16)0.f; z.w = (bf16)0.f;
        d[0] = z;
        d[64] = z;
      }
    }
  } else if (blk < 6144) {
    const int i = (blk - 2048) * 256 + tid;  // over NB*NQ*DD/4 float4s
    float4 v = ((const float4*)proto)[i];
    bf16x4 o;
    o.x = (bf16)v.x; o.y = (bf16)v.y; o.z = (bf16)v.z; o.w = (bf16)v.w;
    ((bf16x4*)proto_b)[i] = o;
  } else {
    const int j = (blk - 6144) * 256 + tid;  // over 4*65536 float4s
    const int w = j >> 16, r = j & 65535;
    const float* src = (w == 0) ? Wq : (w == 1) ? Wk : (w == 2) ? Wv : Wp;
    bf16x4* dst = (w == 0) ? (bf16x4*)Wq_b
                : (w == 3) ? (bf16x4*)Wp_b
                           : (bf16x4*)Wkv_b + (w == 2 ? 65536 : 0);
    float4 v = ((const float4*)src)[r];
    bf16x4 o;
    o.x = (bf16)v.x; o.y = (bf16)v.y; o.z = (bf16)v.z; o.w = (bf16)v.w;
    dst[r] = o;
  }
}

// ---------------- 128x128-tile GEMM, BK=64, double-buffered ----------------
// LDS: [A0|B0|A1|B1], 16KB each; each buf-half is 16 subtiles of [16r][32K].
// EPI 0 = plain bf16 repack-store (q-proj). EPI 2 = S: exp + zeroing + rowsum.
// EPI 4 = f32 direct store (out-proj). EPI 5 = kv dual (k | vT transposed).
#define GB_DBUF 16384
template <int EPI>
__global__ void __launch_bounds__(256, 2)
gemm_bt(const bf16* __restrict__ A, const bf16* __restrict__ Bw,
        void* __restrict__ Cp, void* __restrict__ Cp2,
        int N, int Klen, int Kstride,
        long sA, long sB, long sC,
        const int* __restrict__ cnt, const int* __restrict__ kpad,
        float* __restrict__ denom, float scale, int M) {
  __shared__ alignas(16) bf16 Smem[32768];  // 64KB: A0 B0 A1 B1
  bf16* As = Smem;
  bf16* Bs = Smem + 8192;
  bf16* Rt = Smem;            // epilogue overlay (34.8KB < 64KB)
  const int tid = threadIdx.x;
  const int wave = tid >> 6, lane = tid & 63;
  const int l15 = lane & 15, l4 = lane >> 4;
  const int wm = (wave >> 1) * 64, wn = (wave & 1) * 64;
  const int bx = (EPI == 5) ? blockIdx.y : blockIdx.x;
  const int by = (EPI == 5) ? blockIdx.x : blockIdx.y;
  const int b = blockIdx.z;

  if constexpr (EPI == 2) {
    if (bx * 128 >= kpad[b]) return;
  } else if constexpr (EPI == 5) {
    const int bb = by >> 5, loc = (by & 31) * 128;
    if (loc >= kpad[bb]) return;
  }

  const bf16* Ab = A + (long)b * sA + (long)(by * 128) * Kstride;
  const bf16* Bb = Bw + (long)b * sB + (long)(bx * 128) * Kstride;

  const int srow = lane >> 2, scol = (lane & 3) * 8;
  const bf16* ag[4];
  const bf16* bg[4];
  bf16* al[4];
  bf16* bl[4];
#pragma unroll
  for (int i = 0; i < 4; ++i) {
    const int st = wave * 4 + i, rs = st >> 1, cs = st & 1;
    ag[i] = Ab + (long)(rs * 16 + srow) * Kstride + cs * 32 + scol;
    bg[i] = Bb + (long)(rs * 16 + srow) * Kstride + cs * 32 + scol;
    al[i] = As + st * 512;
    bl[i] = Bs + st * 512;
  }

  f32x4 acc[4][4] = {};

  // prologue: stage tile 0 into buffer 0 (latency exposed once)
#pragma unroll
  for (int i = 0; i < 4; ++i) lds16(ag[i], al[i]);
#pragma unroll
  for (int i = 0; i < 4; ++i) lds16(bg[i], bl[i]);
#pragma unroll
  for (int i = 0; i < 4; ++i) { ag[i] += 64; bg[i] += 64; }
  __syncthreads();

  int cur = 0;
  for (int kt = 0; kt < Klen; kt += 64) {
    // read fragments of current tile
    const bf16* Ac = As + cur * GB_DBUF;
    const bf16* Bc = Bs + cur * GB_DBUF;
    bf16x8 af0[4], af1[4], bf0[4], bf1[4];
    const int ra = (wave >> 1) * 4, rb = (wave & 1) * 4;
#pragma unroll
    for (int t = 0; t < 4; ++t) {
      af0[t] = *(const bf16x8*)(Ac + ((ra + t) * 2 + 0) * 512 + l15 * 32 + l4 * 8);
      af1[t] = *(const bf16x8*)(Ac + ((ra + t) * 2 + 1) * 512 + l15 * 32 + l4 * 8);
      bf0[t] = *(const bf16x8*)(Bc + ((rb + t) * 2 + 0) * 512 + l15 * 32 + l4 * 8);
      bf1[t] = *(const bf16x8*)(Bc + ((rb + t) * 2 + 1) * 512 + l15 * 32 + l4 * 8);
    }
    // issue next-tile prefetch into the other buffer (lands during MFMA)
    if (kt + 64 < Klen) {
      const int nb = (cur ^ 1) * GB_DBUF;
#pragma unroll
      for (int i = 0; i < 4; ++i) lds16(ag[i], al[i] + nb);
#pragma unroll
      for (int i = 0; i < 4; ++i) lds16(bg[i], bl[i] + nb);
#pragma unroll
      for (int i = 0; i < 4; ++i) { ag[i] += 64; bg[i] += 64; }
    }
#pragma unroll
    for (int mt = 0; mt < 4; ++mt)
#pragma unroll
      for (int nt = 0; nt < 4; ++nt) {
        acc[mt][nt] = __builtin_amdgcn_mfma_f32_16x16x32_bf16(af0[mt], bf0[nt],
                                                              acc[mt][nt], 0, 0, 0);
        acc[mt][nt] = __builtin_amdgcn_mfma_f32_16x16x32_bf16(af1[mt], bf1[nt],
                                                              acc[mt][nt], 0, 0, 0);
      }
    __syncthreads();  // prefetch landed (vmcnt0) + all reads done -> swap
    cur ^= 1;
  }

  const int rowBase = by * 128 + wm;
  const int colBase = bx * 128 + wn;
  const int tR = by * 128;
  const int tC = bx * 128;
  // loop ended with __syncthreads(): K-loop LDS dead, Rt overlay safe

  if constexpr (EPI == 2) {
    bf16* C = (bf16*)Cp + (long)b * sC;
    const int nkeep = cnt[b];
    float rs[4][4];
#pragma unroll
    for (int mt = 0; mt < 4; ++mt)
#pragma unroll
      for (int r = 0; r < 4; ++r) rs[mt][r] = 0.f;
#pragma unroll
    for (int nt = 0; nt < 4; ++nt) {
      const bool keep = (colBase + nt * 16 + l15) < nkeep;
#pragma unroll
      for (int mt = 0; mt < 4; ++mt)
#pragma unroll
        for (int r = 0; r < 4; ++r) {
          float p = keep ? __expf(acc[mt][nt][r] * scale) : 0.f;
          rs[mt][r] += p;
          Rt[(wm + mt * 16 + l4 * 4 + r) * RT_LD + wn + nt * 16 + l15] = (bf16)p;
        }
    }
#pragma unroll
    for (int mt = 0; mt < 4; ++mt)
#pragma unroll
      for (int r = 0; r < 4; ++r) {
        float v = rs[mt][r];
        v += __shfl_xor(v, 1, 64);
        v += __shfl_xor(v, 2, 64);
        v += __shfl_xor(v, 4, 64);
        v += __shfl_xor(v, 8, 64);
        if (l15 == 0)
          atomicAdd(&denom[b * M + rowBase + mt * 16 + l4 * 4 + r], v);
      }
    __syncthreads();
    const int r0 = tid >> 2, cq = (tid & 3) * 32;
#pragma unroll
    for (int h = 0; h < 128; h += 64)
#pragma unroll
      for (int j = 0; j < 4; ++j) {
        bf16x8 v = *(const bf16x8*)(Rt + (r0 + h) * RT_LD + cq + j * 8);
        *(bf16x8*)(C + (long)(tR + r0 + h) * N + tC + cq + j * 8) = v;
      }
  } else if constexpr (EPI == 0) {
    bf16* C = (bf16*)Cp;
#pragma unroll
    for (int mt = 0; mt < 4; ++mt)
#pragma unroll
      for (int nt = 0; nt < 4; ++nt)
#pragma unroll
        for (int r = 0; r < 4; ++r)
          Rt[(wm + mt * 16 + l4 * 4 + r) * RT_LD + wn + nt * 16 + l15] =
              (bf16)acc[mt][nt][r];
    __syncthreads();
    const int r0 = tid >> 2, cq = (tid & 3) * 32;
#pragma unroll
    for (int h = 0; h < 128; h += 64)
#pragma unroll
      for (int j = 0; j < 4; ++j) {
        bf16x8 v = *(const bf16x8*)(Rt + (r0 + h) * RT_LD + cq + j * 8);
        *(bf16x8*)(C + (long)(tR + r0 + h) * N + tC + cq + j * 8) = v;
      }
  } else if constexpr (EPI == 4) {
    float* C = (float*)Cp;
#pragma unroll
    for (int mt = 0; mt < 4; ++mt)
#pragma unroll
      for (int nt = 0; nt < 4; ++nt)
#pragma unroll
        for (int r = 0; r < 4; ++r)
          C[(long)(tR + wm + mt * 16 + l4 * 4 + r) * N + tC + wn + nt * 16 + l15] =
              acc[mt][nt][r];
  } else {  // EPI == 5: kv dual epilogue, rows flat over compacted [B][...]
    if (tC < 512) {
      bf16* C = (bf16*)Cp;  // k: [B*NKV][512]
#pragma unroll
      for (int mt = 0; mt < 4; ++mt)
#pragma unroll
        for (int nt = 0; nt < 4; ++nt)
#pragma unroll
          for (int r = 0; r < 4; ++r)
            Rt[(wm + mt * 16 + l4 * 4 + r) * RT_LD + wn + nt * 16 + l15] =
                (bf16)acc[mt][nt][r];
      __syncthreads();
      const int r0 = tid >> 2, cq = (tid & 3) * 32;
#pragma unroll
      for (int h = 0; h < 128; h += 64)
#pragma unroll
        for (int j = 0; j < 4; ++j) {
          bf16x8 v = *(const bf16x8*)(Rt + (r0 + h) * RT_LD + cq + j * 8);
          *(bf16x8*)(C + (long)(tR + r0 + h) * 512 + tC + cq + j * 8) = v;
        }
    } else {
      bf16* C = (bf16*)Cp2;  // vT: [B][512][NKV], transpose via Rt[d][kv]
#pragma unroll
      for (int mt = 0; mt < 4; ++mt) {
        const int r0 = wm + mt * 16 + l4 * 4;
#pragma unroll
        for (int nt = 0; nt < 4; ++nt) {
          const int cloc = wn + nt * 16 + l15;
          bf16x4 o;
          o.x = (bf16)acc[mt][nt][0]; o.y = (bf16)acc[mt][nt][1];
          o.z = (bf16)acc[mt][nt][2]; o.w = (bf16)acc[mt][nt][3];
          *(bf16x4*)(Rt + cloc * RT_LD + r0) = o;
        }
      }
      __syncthreads();
      const int bb = tR >> 12, kvloc = tR & 4095;
      const int d0 = tid >> 2, kvq = (tid & 3) * 32;
#pragma unroll
      for (int h = 0; h < 128; h += 64)
#pragma unroll
        for (int j = 0; j < 4; ++j) {
          bf16x8 v = *(const bf16x8*)(Rt + (d0 + h) * RT_LD + kvq + j * 8);
          *(bf16x8*)(C + (long)bb * DD * NKV + (long)(tC - 512 + d0 + h) * NKV +
                     kvloc + kvq + j * 8) = v;
        }
    }
  }
}

// -------- PV direct: x = (P @ vT^T) / denom, BK=64, double-buffered --------
// Tile 64q x 128d, K = kpad[b] (compacted). Grid (16,4,8).
// LDS: [A0|B0|A1|B1] = 48KB -> 3 blocks/CU.
#define PV_DBUF 12288
__global__ void __launch_bounds__(256, 3)
pv_direct(const bf16* __restrict__ P, const bf16* __restrict__ vT,
          const float* __restrict__ denom, const int* __restrict__ kpad,
          bf16* __restrict__ x) {
  __shared__ alignas(16) bf16 Smem[24576];  // 48KB
  bf16* As = Smem;
  bf16* Bs = Smem + 4096;
  bf16* Rt = Smem;  // epilogue overlay: 64*RT_LD = 8704 elts
  const int tid = threadIdx.x;
  const int wave = tid >> 6, lane = tid & 63;
  const int l15 = lane & 15, l4 = lane >> 4;
  const int wm = (wave >> 1) * 32, wn = (wave & 1) * 64;
  const int qB = blockIdx.x * 64;
  const int dB = blockIdx.y * 128;
  const int b = blockIdx.z;
  const int Kb = kpad[b];

  const bf16* Ab = P + (long)b * NQ * NKV + (long)qB * NKV;
  const bf16* Bb = vT + (long)b * DD * NKV + (long)dB * NKV;

  const int srow = lane >> 2, scol = (lane & 3) * 8;
  const bf16* ag[2];
  const bf16* bg[4];
  bf16* al[2];
  bf16* bl[4];
#pragma unroll
  for (int i = 0; i < 2; ++i) {
    const int st = wave * 2 + i, rs = st >> 1, cs = st & 1;
    ag[i] = Ab + (long)(rs * 16 + srow) * NKV + cs * 32 + scol;
    al[i] = As + st * 512;
  }
#pragma unroll
  for (int i = 0; i < 4; ++i) {
    const int st = wave * 4 + i, rs = st >> 1, cs = st & 1;
    bg[i] = Bb + (long)(rs * 16 + srow) * NKV + cs * 32 + scol;
    bl[i] = Bs + st * 512;
  }

  f32x4 acc[2][4] = {};

  // prologue: stage tile 0 into buffer 0
#pragma unroll
  for (int i = 0; i < 2; ++i) lds16(ag[i], al[i]);
#pragma unroll
  for (int i = 0; i < 4; ++i) lds16(bg[i], bl[i]);
#pragma unroll
  for (int i = 0; i < 2; ++i) ag[i] += 64;
#pragma unroll
  for (int i = 0; i < 4; ++i) bg[i] += 64;
  __syncthreads();

  int cur = 0;
  for (int kt = 0; kt < Kb; kt += 64) {
    const bf16* Ac = As + cur * PV_DBUF;
    const bf16* Bc = Bs + cur * PV_DBUF;
    bf16x8 af0[2], af1[2], bf0[4], bf1[4];
    const int ra = (wave >> 1) * 2, rb = (wave & 1) * 4;
#pragma unroll
    for (int t = 0; t < 2; ++t) {
      af0[t] = *(const bf16x8*)(Ac + ((ra + t) * 2 + 0) * 512 + l15 * 32 + l4 * 8);
      af1[t] = *(const bf16x8*)(Ac + ((ra + t) * 2 + 1) * 512 + l15 * 32 + l4 * 8);
    }
#pragma unroll
    for (int t = 0; t < 4; ++t) {
      bf0[t] = *(const bf16x8*)(Bc + ((rb + t) * 2 + 0) * 512 + l15 * 32 + l4 * 8);
      bf1[t] = *(const bf16x8*)(Bc + ((rb + t) * 2 + 1) * 512 + l15 * 32 + l4 * 8);
    }
    if (kt + 64 < Kb) {
      const int nb = (cur ^ 1) * PV_DBUF;
#pragma unroll
      for (int i = 0; i < 2; ++i) lds16(ag[i], al[i] + nb);
#pragma unroll
      for (int i = 0; i < 4; ++i) lds16(bg[i], bl[i] + nb);
#pragma unroll
      for (int i = 0; i < 2; ++i) ag[i] += 64;
#pragma unroll
      for (int i = 0; i < 4; ++i) bg[i] += 64;
    }
#pragma unroll
    for (int mt = 0; mt < 2; ++mt)
#pragma unroll
      for (int nt = 0; nt < 4; ++nt) {
        acc[mt][nt] = __builtin_amdgcn_mfma_f32_16x16x32_bf16(af0[mt], bf0[nt],
                                                              acc[mt][nt], 0, 0, 0);
        acc[mt][nt] = __builtin_amdgcn_mfma_f32_16x16x32_bf16(af1[mt], bf1[nt],
                                                              acc[mt][nt], 0, 0, 0);
      }
    __syncthreads();
    cur ^= 1;
  }

  // loop ended with barrier: Rt overlay safe
#pragma unroll
  for (int mt = 0; mt < 2; ++mt)
#pragma unroll
    for (int r = 0; r < 4; ++r) {
      const int row = wm + mt * 16 + l4 * 4 + r;
      const float inv = 1.0f / denom[b * NQ + qB + row];
#pragma unroll
      for (int nt = 0; nt < 4; ++nt)
        Rt[row * RT_LD + wn + nt * 16 + l15] = (bf16)(acc[mt][nt][r] * inv);
    }
  __syncthreads();
  const int r0 = tid >> 2, cq = (tid & 3) * 32;
#pragma unroll
  for (int j = 0; j < 4; ++j) {
    bf16x8 v = *(const bf16x8*)(Rt + r0 * RT_LD + cq + j * 8);
    *(bf16x8*)(x + (long)(b * NQ + qB + r0) * DD + dB + cq + j * 8) = v;
  }
}

extern "C" void kernel_launch(void* const* d_in, const int* in_sizes, int n_in,
                              void* d_out, int out_size, void* d_ws, size_t ws_size,
                              hipStream_t stream) {
  const float* proto = (const float*)d_in[0];
  const float* qx    = (const float*)d_in[1];
  const void*  mask  = d_in[2];
  const float* Wq    = (const float*)d_in[3];
  const float* Wk    = (const float*)d_in[4];
  const float* Wv    = (const float*)d_in[5];
  const float* Wproj = (const float*)d_in[6];
  float* out = (float*)d_out;

  char* w = (char*)d_ws;
  int*   cnt   = (int*)(w + 64);
  int*   kpadA = (int*)(w + 128);
  float* denom = (float*)(w + 4096);
  size_t off = 65536;
  bf16* Wq_b  = (bf16*)(w + off); off += (size_t)DD * DD * 2;
  bf16* Wkv_b = (bf16*)(w + off); off += (size_t)DD * DD * 4;
  bf16* Wp_b  = (bf16*)(w + off); off += (size_t)DD * DD * 2;
  int*  idx   = (int*)(w + off);  off += (size_t)NB * NKV * 4;
  bf16* q_b   = (bf16*)(w + off); off += (size_t)NB * NQ * DD * 2;   // 8MB
  bf16* k_b   = (bf16*)(w + off); off += (size_t)NB * NKV * DD * 2;  // 32MB
  bf16* vT_b  = (bf16*)(w + off); off += (size_t)NB * NKV * DD * 2;  // 32MB
  bf16* x_b   = (bf16*)(w + off); off += (size_t)NB * NQ * DD * 2;   // 8MB
  size_t off_pp = off;
  bf16* proto_b = (bf16*)(w + off); off += (size_t)NB * NQ * DD * 2;
  bf16* qc_b    = (bf16*)(w + off);
  bf16* P       = (bf16*)(w + off_pp);   // 64MB, overlays proto/qc (dead by S)

  scan_mask<<<8, 256, 0, stream>>>(mask, idx, cnt, kpadA, denom);
  prep<<<7168, 256, 0, stream>>>(qx, idx, cnt, kpadA, qc_b,
                                 proto, proto_b, Wq, Wk, Wv, Wproj,
                                 Wq_b, Wkv_b, Wp_b);

  const float scale = 0.04419417382415922f;  // 512^-0.5

  // q = proto @ Wq^T  (128x128 tiles, grid (4,64))
  gemm_bt<0><<<dim3(4, 64, 1), 256, 0, stream>>>(
      proto_b, Wq_b, q_b, nullptr, DD, DD, DD, 0L, 0L, 0L,
      cnt, kpadA, nullptr, 0.f, 0);
  // k | vT = qc @ [Wk;Wv]^T  compacted rows
  gemm_bt<5><<<dim3(256, 8, 1), 256, 0, stream>>>(
      qc_b, Wkv_b, k_b, vT_b, 1024, DD, DD, 0L, 0L, 0L,
      cnt, kpadA, nullptr, 0.f, 0);
  // P = exp(scale * q @ k^T), zero cols >= cnt[b]; denom += row sums
  gemm_bt<2><<<dim3(NKV / 128, NQ / 128, NB), 256, 0, stream>>>(
      q_b, k_b, P, nullptr, NKV, DD, DD,
      (long)NQ * DD, (long)NKV * DD, (long)NQ * NKV,
      cnt, kpadA, denom, scale, NQ);
  // x = (P @ vT^T) / denom
  pv_direct<<<dim3(16, 4, 8), 256, 0, stream>>>(P, vT_b, denom, kpadA, x_b);
  // out = x @ Wproj^T  fp32
  gemm_bt<4><<<dim3(4, 64, 1), 256, 0, stream>>>(
      x_b, Wp_b, out, nullptr, DD, DD, DD, 0L, 0L, 0L,
      cnt, kpadA, nullptr, 0.f, 0);
}

// Round 5
// 308.329 us; speedup vs baseline: 1.0633x; 1.0633x over previous
//
#include <hip/hip_runtime.h>
#include <hip/hip_bf16.h>
#include <stdint.h>

// QSCrossAttention: B=8, Nq=1024, Nkv=4096, D=512, fp32 I/O, bf16 MFMA compute.
// R13: depth-3 counted-vmcnt pipeline (T4). Four 2-phase variants all measured
//      66-74us because every barrier drained vmcnt(0), exposing L2/L3 latency
//      each K-step. Now: 3 LDS buffers, BK=32; per iter:
//      s_waitcnt vmcnt(4) [tile t landed, t+1 in flight] -> raw s_barrier ->
//      sched_barrier(0) -> issue tile t+2 -> ds_read t -> MFMA. Loads get ~2
//      iterations of flight. 48KB LDS -> 3 blk/CU gemm, 36KB -> 4 blk/CU pv.

typedef __bf16 bf16;
typedef bf16 bf16x8 __attribute__((ext_vector_type(8)));
typedef bf16 bf16x4 __attribute__((ext_vector_type(4)));
typedef float f32x4 __attribute__((ext_vector_type(4)));

#define NB 8
#define NQ 1024
#define NKV 4096
#define DD 512
#define RT_LD 136  // repack leading dim for 128-col tiles (272B rows)

// Async global->LDS, 16B per lane. g is per-lane global src; l must be the
// WAVE-UNIFORM LDS base (HW deposits at base + lane*16).
__device__ __forceinline__ void lds16(const bf16* g, bf16* l) {
  __builtin_amdgcn_global_load_lds(
      (const __attribute__((address_space(1))) unsigned int*)g,
      (__attribute__((address_space(3))) unsigned int*)l, 16, 0, 0);
}

// ---- scan_mask: 3-mode sniff + denom zero + per-batch prefix scan ---------
// mode 0: int32 0/1; mode 1: float 0.0/1.0; mode 2: bytes.
__global__ void scan_mask(const void* __restrict__ mask,
                          int* __restrict__ idx, int* __restrict__ cnt,
                          int* __restrict__ kpad, float* __restrict__ denom) {
  const int b = blockIdx.x, tid = threadIdx.x;
  // zero this batch's denominators
  for (int i = tid; i < NQ; i += 256) denom[b * NQ + i] = 0.f;

  // sniff the first 8192 words (32KB) -- whole byte-mask / prefix of word-mask
  __shared__ int s0, s1;
  if (tid == 0) { s0 = 0; s1 = 0; }
  __syncthreads();
  {
    const unsigned* mw = (const unsigned*)mask;
    int b0 = 0, b1 = 0;
    for (int i = tid; i < 8192; i += 256) {
      unsigned v = mw[i];
      if (v > 1u) b0 = 1;
      if (v != 0u && v != 0x3F800000u) b1 = 1;
    }
    if (b0) atomicOr(&s0, 1);
    if (b1) atomicOr(&s1, 1);
  }
  __syncthreads();
  const int mode = (s0 == 0) ? 0 : ((s1 == 0) ? 1 : 2);

  __shared__ int ps[256];
  unsigned bits = 0;
  int c = 0;
  const int base = tid * 16;
  for (int i = 0; i < 16; ++i) {
    const int col = base + i;
    bool k;
    if (mode == 0)      k = ((const int*)mask)[b * NKV + col] != 0;
    else if (mode == 1) k = ((const float*)mask)[b * NKV + col] != 0.f;
    else                k = ((const unsigned char*)mask)[b * NKV + col] != 0;
    bits |= (unsigned)k << i;
    c += k;
  }
  ps[tid] = c;
  __syncthreads();
  for (int s = 1; s < 256; s <<= 1) {
    int v = (tid >= s) ? ps[tid - s] : 0;
    __syncthreads();
    ps[tid] += v;
    __syncthreads();
  }
  int off = ps[tid] - c;
  for (int i = 0; i < 16; ++i)
    if ((bits >> i) & 1) idx[b * NKV + off++] = base + i;
  if (tid == 255) {
    cnt[b] = ps[255];
    kpad[b] = (ps[255] + 127) & ~127;
  }
}

// ---- prep: gather_qx (blk<2048) | cvt proto (<6144) | cvt weights ---------
__global__ void prep(const float* __restrict__ qx, const int* __restrict__ idx,
                     const int* __restrict__ cnt, const int* __restrict__ kpad,
                     bf16* __restrict__ qc,
                     const float* __restrict__ proto, bf16* __restrict__ proto_b,
                     const float* __restrict__ Wq, const float* __restrict__ Wk,
                     const float* __restrict__ Wv, const float* __restrict__ Wp,
                     bf16* __restrict__ Wq_b, bf16* __restrict__ Wkv_b,
                     bf16* __restrict__ Wp_b) {
  const int blk = blockIdx.x, tid = threadIdx.x;
  if (blk < 2048) {
    // gather: qc[b][r] = bf16(qx[b][idx[b][r]]) for r<cnt, zeros r in [cnt,kpad)
    const int b = blk >> 8, bx = blk & 255;
    const int wave = tid >> 6, lane = tid & 63;
    const int r0 = bx * 16 + wave * 4;
    const int n = cnt[b];
    const int kp = kpad[b];
#pragma unroll
    for (int j = 0; j < 4; ++j) {
      const int row = r0 + j;
      if (row >= kp) return;
      bf16x4* d = (bf16x4*)(qc + ((long)b * NKV + row) * DD) + lane;
      if (row < n) {
        const int src = idx[b * NKV + row];
        const float4* s = (const float4*)(qx + ((long)b * NKV + src) * DD) + lane;
        float4 v0 = s[0], v1 = s[64];
        bf16x4 o0, o1;
        o0.x = (bf16)v0.x; o0.y = (bf16)v0.y; o0.z = (bf16)v0.z; o0.w = (bf16)v0.w;
        o1.x = (bf16)v1.x; o1.y = (bf16)v1.y; o1.z = (bf16)v1.z; o1.w = (bf16)v1.w;
        d[0] = o0;
        d[64] = o1;
      } else {
        bf16x4 z;
        z.x = (bf16)0.f; z.y = (bf16)0.f; z.z = (bf16)0.f; z.w = (bf16)0.f;
        d[0] = z;
        d[64] = z;
      }
    }
  } else if (blk < 6144) {
    const int i = (blk - 2048) * 256 + tid;  // over NB*NQ*DD/4 float4s
    float4 v = ((const float4*)proto)[i];
    bf16x4 o;
    o.x = (bf16)v.x; o.y = (bf16)v.y; o.z = (bf16)v.z; o.w = (bf16)v.w;
    ((bf16x4*)proto_b)[i] = o;
  } else {
    const int j = (blk - 6144) * 256 + tid;  // over 4*65536 float4s
    const int w = j >> 16, r = j & 65535;
    const float* src = (w == 0) ? Wq : (w == 1) ? Wk : (w == 2) ? Wv : Wp;
    bf16x4* dst = (w == 0) ? (bf16x4*)Wq_b
                : (w == 3) ? (bf16x4*)Wp_b
                           : (bf16x4*)Wkv_b + (w == 2 ? 65536 : 0);
    float4 v = ((const float4*)src)[r];
    bf16x4 o;
    o.x = (bf16)v.x; o.y = (bf16)v.y; o.z = (bf16)v.z; o.w = (bf16)v.w;
    dst[r] = o;
  }
}

// ------------- 128x128-tile GEMM, BK=32, depth-3 counted-vmcnt -------------
// LDS: 3 buffers x (A 8KB | B 8KB) = 48KB. Per wave per tile: 4 lds16.
// Steady-state wait: vmcnt(4) (next tile in flight). Tail: vmcnt(0).
// EPI 0 = plain bf16 repack-store (q-proj). EPI 2 = S: exp + zeroing + rowsum.
// EPI 4 = f32 direct store (out-proj). EPI 5 = kv dual (k | vT transposed).
template <int EPI>
__global__ void __launch_bounds__(256, 3)
gemm_bt(const bf16* __restrict__ A, const bf16* __restrict__ Bw,
        void* __restrict__ Cp, void* __restrict__ Cp2,
        int N, int Klen, int Kstride,
        long sA, long sB, long sC,
        const int* __restrict__ cnt, const int* __restrict__ kpad,
        float* __restrict__ denom, float scale, int M) {
  __shared__ alignas(16) bf16 Smem[24576];  // 48KB: 3 x [A(4096) B(4096)]
  bf16* Rt = Smem;            // epilogue overlay (34.8KB < 48KB)
  const int tid = threadIdx.x;
  const int wave = tid >> 6, lane = tid & 63;
  const int l15 = lane & 15, l4 = lane >> 4;
  const int wm = (wave >> 1) * 64, wn = (wave & 1) * 64;
  const int bx = (EPI == 5) ? blockIdx.y : blockIdx.x;
  const int by = (EPI == 5) ? blockIdx.x : blockIdx.y;
  const int b = blockIdx.z;

  if constexpr (EPI == 2) {
    if (bx * 128 >= kpad[b]) return;
  } else if constexpr (EPI == 5) {
    const int bb = by >> 5, loc = (by & 31) * 128;
    if (loc >= kpad[bb]) return;
  }

  const bf16* Ab = A + (long)b * sA + (long)(by * 128) * Kstride;
  const bf16* Bb = Bw + (long)b * sB + (long)(bx * 128) * Kstride;

  const int srow = lane >> 2, scol = (lane & 3) * 8;
  const int c0 = wave * 2, c1 = wave * 2 + 1;
  // per-lane global sources; wave-uniform LDS bases (subtile = [16r][32k], 1KB)
  const bf16* g0 = Ab + (long)(c0 * 16 + srow) * Kstride + scol;
  const bf16* g1 = Ab + (long)(c1 * 16 + srow) * Kstride + scol;
  const bf16* g2 = Bb + (long)(c0 * 16 + srow) * Kstride + scol;
  const bf16* g3 = Bb + (long)(c1 * 16 + srow) * Kstride + scol;
  bf16* l0 = Smem + c0 * 512;
  bf16* l1 = Smem + c1 * 512;
  bf16* l2 = Smem + 4096 + c0 * 512;
  bf16* l3 = Smem + 4096 + c1 * 512;

  f32x4 acc[4][4] = {};
  const int nt = Klen >> 5;

  // stage tile into buffer bb, advance global pointers by 32 cols
#define GSTAGE(bb)                                            \
  do {                                                        \
    const int o_ = (bb) * 8192;                               \
    lds16(g0, l0 + o_); lds16(g1, l1 + o_);                   \
    lds16(g2, l2 + o_); lds16(g3, l3 + o_);                   \
    g0 += 32; g1 += 32; g2 += 32; g3 += 32;                   \
  } while (0)

  GSTAGE(0);
  GSTAGE(1);
  int rd = 0, wr = 2;
  for (int t = 0; t < nt; ++t) {
    if (t + 1 < nt) {
      asm volatile("s_waitcnt vmcnt(4)" ::: "memory");
    } else {
      asm volatile("s_waitcnt vmcnt(0)" ::: "memory");
    }
    __builtin_amdgcn_s_barrier();
    __builtin_amdgcn_sched_barrier(0);
    if (t + 2 < nt) GSTAGE(wr);
    wr = (wr == 2) ? 0 : wr + 1;
    const bf16* Ac = Smem + rd * 8192;
    const bf16* Bc = Ac + 4096;
    rd = (rd == 2) ? 0 : rd + 1;
    bf16x8 af[4], bfr[4];
#pragma unroll
    for (int t2 = 0; t2 < 4; ++t2) {
      af[t2]  = *(const bf16x8*)(Ac + (wm + t2 * 16 + l15) * 32 + l4 * 8);
      bfr[t2] = *(const bf16x8*)(Bc + (wn + t2 * 16 + l15) * 32 + l4 * 8);
    }
#pragma unroll
    for (int mt = 0; mt < 4; ++mt)
#pragma unroll
      for (int nt2 = 0; nt2 < 4; ++nt2)
        acc[mt][nt2] = __builtin_amdgcn_mfma_f32_16x16x32_bf16(af[mt], bfr[nt2],
                                                               acc[mt][nt2], 0, 0, 0);
  }
#undef GSTAGE
  __syncthreads();  // K-loop LDS dead before Rt overlay

  const int rowBase = by * 128 + wm;
  const int colBase = bx * 128 + wn;
  const int tR = by * 128;
  const int tC = bx * 128;

  if constexpr (EPI == 2) {
    bf16* C = (bf16*)Cp + (long)b * sC;
    const int nkeep = cnt[b];
    float rs[4][4];
#pragma unroll
    for (int mt = 0; mt < 4; ++mt)
#pragma unroll
      for (int r = 0; r < 4; ++r) rs[mt][r] = 0.f;
#pragma unroll
    for (int nt2 = 0; nt2 < 4; ++nt2) {
      const bool keep = (colBase + nt2 * 16 + l15) < nkeep;
#pragma unroll
      for (int mt = 0; mt < 4; ++mt)
#pragma unroll
        for (int r = 0; r < 4; ++r) {
          float p = keep ? __expf(acc[mt][nt2][r] * scale) : 0.f;
          rs[mt][r] += p;
          Rt[(wm + mt * 16 + l4 * 4 + r) * RT_LD + wn + nt2 * 16 + l15] = (bf16)p;
        }
    }
#pragma unroll
    for (int mt = 0; mt < 4; ++mt)
#pragma unroll
      for (int r = 0; r < 4; ++r) {
        float v = rs[mt][r];
        v += __shfl_xor(v, 1, 64);
        v += __shfl_xor(v, 2, 64);
        v += __shfl_xor(v, 4, 64);
        v += __shfl_xor(v, 8, 64);
        if (l15 == 0)
          atomicAdd(&denom[b * M + rowBase + mt * 16 + l4 * 4 + r], v);
      }
    __syncthreads();
    const int r0 = tid >> 2, cq = (tid & 3) * 32;
#pragma unroll
    for (int h = 0; h < 128; h += 64)
#pragma unroll
      for (int j = 0; j < 4; ++j) {
        bf16x8 v = *(const bf16x8*)(Rt + (r0 + h) * RT_LD + cq + j * 8);
        *(bf16x8*)(C + (long)(tR + r0 + h) * N + tC + cq + j * 8) = v;
      }
  } else if constexpr (EPI == 0) {
    bf16* C = (bf16*)Cp;
#pragma unroll
    for (int mt = 0; mt < 4; ++mt)
#pragma unroll
      for (int nt2 = 0; nt2 < 4; ++nt2)
#pragma unroll
        for (int r = 0; r < 4; ++r)
          Rt[(wm + mt * 16 + l4 * 4 + r) * RT_LD + wn + nt2 * 16 + l15] =
              (bf16)acc[mt][nt2][r];
    __syncthreads();
    const int r0 = tid >> 2, cq = (tid & 3) * 32;
#pragma unroll
    for (int h = 0; h < 128; h += 64)
#pragma unroll
      for (int j = 0; j < 4; ++j) {
        bf16x8 v = *(const bf16x8*)(Rt + (r0 + h) * RT_LD + cq + j * 8);
        *(bf16x8*)(C + (long)(tR + r0 + h) * N + tC + cq + j * 8) = v;
      }
  } else if constexpr (EPI == 4) {
    float* C = (float*)Cp;
#pragma unroll
    for (int mt = 0; mt < 4; ++mt)
#pragma unroll
      for (int nt2 = 0; nt2 < 4; ++nt2)
#pragma unroll
        for (int r = 0; r < 4; ++r)
          C[(long)(tR + wm + mt * 16 + l4 * 4 + r) * N + tC + wn + nt2 * 16 + l15] =
              acc[mt][nt2][r];
  } else {  // EPI == 5: kv dual epilogue, rows flat over compacted [B][...]
    if (tC < 512) {
      bf16* C = (bf16*)Cp;  // k: [B*NKV][512]
#pragma unroll
      for (int mt = 0; mt < 4; ++mt)
#pragma unroll
        for (int nt2 = 0; nt2 < 4; ++nt2)
#pragma unroll
          for (int r = 0; r < 4; ++r)
            Rt[(wm + mt * 16 + l4 * 4 + r) * RT_LD + wn + nt2 * 16 + l15] =
                (bf16)acc[mt][nt2][r];
      __syncthreads();
      const int r0 = tid >> 2, cq = (tid & 3) * 32;
#pragma unroll
      for (int h = 0; h < 128; h += 64)
#pragma unroll
        for (int j = 0; j < 4; ++j) {
          bf16x8 v = *(const bf16x8*)(Rt + (r0 + h) * RT_LD + cq + j * 8);
          *(bf16x8*)(C + (long)(tR + r0 + h) * 512 + tC + cq + j * 8) = v;
        }
    } else {
      bf16* C = (bf16*)Cp2;  // vT: [B][512][NKV], transpose via Rt[d][kv]
#pragma unroll
      for (int mt = 0; mt < 4; ++mt) {
        const int r0 = wm + mt * 16 + l4 * 4;
#pragma unroll
        for (int nt2 = 0; nt2 < 4; ++nt2) {
          const int cloc = wn + nt2 * 16 + l15;
          bf16x4 o;
          o.x = (bf16)acc[mt][nt2][0]; o.y = (bf16)acc[mt][nt2][1];
          o.z = (bf16)acc[mt][nt2][2]; o.w = (bf16)acc[mt][nt2][3];
          *(bf16x4*)(Rt + cloc * RT_LD + r0) = o;
        }
      }
      __syncthreads();
      const int bb = tR >> 12, kvloc = tR & 4095;
      const int d0 = tid >> 2, kvq = (tid & 3) * 32;
#pragma unroll
      for (int h = 0; h < 128; h += 64)
#pragma unroll
        for (int j = 0; j < 4; ++j) {
          bf16x8 v = *(const bf16x8*)(Rt + (d0 + h) * RT_LD + kvq + j * 8);
          *(bf16x8*)(C + (long)bb * DD * NKV + (long)(tC - 512 + d0 + h) * NKV +
                     kvloc + kvq + j * 8) = v;
        }
    }
  }
}

// ------ PV direct: x = (P @ vT^T)/denom, BK=32, depth-3 counted-vmcnt ------
// Tile 64q x 128d, K = kpad[b]. Grid (16,4,8). LDS 3 x (A 4KB | B 8KB) = 36KB.
// Per wave per tile: 3 lds16 -> steady wait vmcnt(3), tail vmcnt(0).
__global__ void __launch_bounds__(256, 4)
pv_direct(const bf16* __restrict__ P, const bf16* __restrict__ vT,
          const float* __restrict__ denom, const int* __restrict__ kpad,
          bf16* __restrict__ x) {
  __shared__ alignas(16) bf16 Smem[18432];  // 36KB: 3 x [A(2048) B(4096)]
  bf16* Rt = Smem;  // epilogue overlay: 64*RT_LD = 8704 elts
  const int tid = threadIdx.x;
  const int wave = tid >> 6, lane = tid & 63;
  const int l15 = lane & 15, l4 = lane >> 4;
  const int wm = (wave >> 1) * 32, wn = (wave & 1) * 64;
  const int qB = blockIdx.x * 64;
  const int dB = blockIdx.y * 128;
  const int b = blockIdx.z;
  const int Kb = kpad[b];

  const bf16* Ab = P + (long)b * NQ * NKV + (long)qB * NKV;
  const bf16* Bb = vT + (long)b * DD * NKV + (long)dB * NKV;

  const int srow = lane >> 2, scol = (lane & 3) * 8;
  const int c0 = wave * 2, c1 = wave * 2 + 1;
  const bf16* ga  = Ab + (long)(wave * 16 + srow) * NKV + scol;
  const bf16* gb0 = Bb + (long)(c0 * 16 + srow) * NKV + scol;
  const bf16* gb1 = Bb + (long)(c1 * 16 + srow) * NKV + scol;
  bf16* la  = Smem + wave * 512;
  bf16* lb0 = Smem + 2048 + c0 * 512;
  bf16* lb1 = Smem + 2048 + c1 * 512;

  f32x4 acc[2][4] = {};
  const int nt = Kb >> 5;

#define PSTAGE(bb)                                           \
  do {                                                       \
    const int o_ = (bb) * 6144;                              \
    lds16(ga, la + o_); lds16(gb0, lb0 + o_);                \
    lds16(gb1, lb1 + o_);                                    \
    ga += 32; gb0 += 32; gb1 += 32;                          \
  } while (0)

  PSTAGE(0);
  PSTAGE(1);
  int rd = 0, wr = 2;
  for (int t = 0; t < nt; ++t) {
    if (t + 1 < nt) {
      asm volatile("s_waitcnt vmcnt(3)" ::: "memory");
    } else {
      asm volatile("s_waitcnt vmcnt(0)" ::: "memory");
    }
    __builtin_amdgcn_s_barrier();
    __builtin_amdgcn_sched_barrier(0);
    if (t + 2 < nt) PSTAGE(wr);
    wr = (wr == 2) ? 0 : wr + 1;
    const bf16* Ac = Smem + rd * 6144;
    const bf16* Bc = Ac + 2048;
    rd = (rd == 2) ? 0 : rd + 1;
    bf16x8 af[2], bfr[4];
#pragma unroll
    for (int t2 = 0; t2 < 2; ++t2)
      af[t2] = *(const bf16x8*)(Ac + (wm + t2 * 16 + l15) * 32 + l4 * 8);
#pragma unroll
    for (int t2 = 0; t2 < 4; ++t2)
      bfr[t2] = *(const bf16x8*)(Bc + (wn + t2 * 16 + l15) * 32 + l4 * 8);
#pragma unroll
    for (int mt = 0; mt < 2; ++mt)
#pragma unroll
      for (int nt2 = 0; nt2 < 4; ++nt2)
        acc[mt][nt2] = __builtin_amdgcn_mfma_f32_16x16x32_bf16(af[mt], bfr[nt2],
                                                               acc[mt][nt2], 0, 0, 0);
  }
#undef PSTAGE
  __syncthreads();  // K-loop LDS dead before Rt overlay

#pragma unroll
  for (int mt = 0; mt < 2; ++mt)
#pragma unroll
    for (int r = 0; r < 4; ++r) {
      const int row = wm + mt * 16 + l4 * 4 + r;
      const float inv = 1.0f / denom[b * NQ + qB + row];
#pragma unroll
      for (int nt2 = 0; nt2 < 4; ++nt2)
        Rt[row * RT_LD + wn + nt2 * 16 + l15] = (bf16)(acc[mt][nt2][r] * inv);
    }
  __syncthreads();
  const int r0 = tid >> 2, cq = (tid & 3) * 32;
#pragma unroll
  for (int j = 0; j < 4; ++j) {
    bf16x8 v = *(const bf16x8*)(Rt + r0 * RT_LD + cq + j * 8);
    *(bf16x8*)(x + (long)(b * NQ + qB + r0) * DD + dB + cq + j * 8) = v;
  }
}

extern "C" void kernel_launch(void* const* d_in, const int* in_sizes, int n_in,
                              void* d_out, int out_size, void* d_ws, size_t ws_size,
                              hipStream_t stream) {
  const float* proto = (const float*)d_in[0];
  const float* qx    = (const float*)d_in[1];
  const void*  mask  = d_in[2];
  const float* Wq    = (const float*)d_in[3];
  const float* Wk    = (const float*)d_in[4];
  const float* Wv    = (const float*)d_in[5];
  const float* Wproj = (const float*)d_in[6];
  float* out = (float*)d_out;

  char* w = (char*)d_ws;
  int*   cnt   = (int*)(w + 64);
  int*   kpadA = (int*)(w + 128);
  float* denom = (float*)(w + 4096);
  size_t off = 65536;
  bf16* Wq_b  = (bf16*)(w + off); off += (size_t)DD * DD * 2;
  bf16* Wkv_b = (bf16*)(w + off); off += (size_t)DD * DD * 4;
  bf16* Wp_b  = (bf16*)(w + off); off += (size_t)DD * DD * 2;
  int*  idx   = (int*)(w + off);  off += (size_t)NB * NKV * 4;
  bf16* q_b   = (bf16*)(w + off); off += (size_t)NB * NQ * DD * 2;   // 8MB
  bf16* k_b   = (bf16*)(w + off); off += (size_t)NB * NKV * DD * 2;  // 32MB
  bf16* vT_b  = (bf16*)(w + off); off += (size_t)NB * NKV * DD * 2;  // 32MB
  bf16* x_b   = (bf16*)(w + off); off += (size_t)NB * NQ * DD * 2;   // 8MB
  size_t off_pp = off;
  bf16* proto_b = (bf16*)(w + off); off += (size_t)NB * NQ * DD * 2;
  bf16* qc_b    = (bf16*)(w + off);
  bf16* P       = (bf16*)(w + off_pp);   // 64MB, overlays proto/qc (dead by S)

  scan_mask<<<8, 256, 0, stream>>>(mask, idx, cnt, kpadA, denom);
  prep<<<7168, 256, 0, stream>>>(qx, idx, cnt, kpadA, qc_b,
                                 proto, proto_b, Wq, Wk, Wv, Wproj,
                                 Wq_b, Wkv_b, Wp_b);

  const float scale = 0.04419417382415922f;  // 512^-0.5

  // q = proto @ Wq^T  (128x128 tiles, grid (4,64))
  gemm_bt<0><<<dim3(4, 64, 1), 256, 0, stream>>>(
      proto_b, Wq_b, q_b, nullptr, DD, DD, DD, 0L, 0L, 0L,
      cnt, kpadA, nullptr, 0.f, 0);
  // k | vT = qc @ [Wk;Wv]^T  compacted rows
  gemm_bt<5><<<dim3(256, 8, 1), 256, 0, stream>>>(
      qc_b, Wkv_b, k_b, vT_b, 1024, DD, DD, 0L, 0L, 0L,
      cnt, kpadA, nullptr, 0.f, 0);
  // P = exp(scale * q @ k^T), zero cols >= cnt[b]; denom += row sums
  gemm_bt<2><<<dim3(NKV / 128, NQ / 128, NB), 256, 0, stream>>>(
      q_b, k_b, P, nullptr, NKV, DD, DD,
      (long)NQ * DD, (long)NKV * DD, (long)NQ * NKV,
      cnt, kpadA, denom, scale, NQ);
  // x = (P @ vT^T) / denom
  pv_direct<<<dim3(16, 4, 8), 256, 0, stream>>>(P, vT_b, denom, kpadA, x_b);
  // out = x @ Wproj^T  fp32
  gemm_bt<4><<<dim3(4, 64, 1), 256, 0, stream>>>(
      x_b, Wp_b, out, nullptr, DD, DD, DD, 0L, 0L, 0L,
      cnt, kpadA, nullptr, 0.f, 0);
}